// Round 3
// baseline (791.749 us; speedup 1.0000x reference)
//
#include <hip/hip_runtime.h>
#include <hip/hip_bf16.h>
#include <cstdint>

#define NN   50000
#define EE   800000
#define DIN_ 256
#define HD_  256     // H*DH
#define DH_  64
#define NH_  4
#define NC_  10
#define NG_  100
#define EPS_ 1e-4f
#define SLOPE_ 0.01f

__device__ __forceinline__ float leaky(float x) { return x >= 0.f ? x : SLOPE_ * x; }
__device__ __forceinline__ float sigm(float x)  { return 1.f / (1.f + __expf(-x)); }

// ---------------- init: zero deg/cursor/gsum/gcnt ----------------
__global__ void init_zero(int* deg, int* cursor, float* gsum, float* gcnt) {
    int i = blockIdx.x * 256 + threadIdx.x;
    if (i < NN) { deg[i] = 0; cursor[i] = 0; }
    if (i < NG_ * NC_) gsum[i] = 0.f;
    if (i < NG_) gcnt[i] = 0.f;
}

// ---------------- GEMM: h = x @ W_feat  (fp32) ----------------
__global__ __launch_bounds__(256) void gemm_h(const float* __restrict__ x,
                                              const float* __restrict__ w,
                                              float* __restrict__ hfeat) {
    __shared__ float As[32][68];
    __shared__ float Bs[32][68];
    const int tid = threadIdx.x;
    const int row0 = blockIdx.x * 64;
    const int col0 = blockIdx.y * 64;
    const int tx = tid & 15, ty = tid >> 4;
    const int lr = tid >> 2, lk = (tid & 3) * 8;
    const int wk = tid >> 3, wn = (tid & 7) * 8;

    float acc[4][4] = {};

    for (int k0 = 0; k0 < DIN_; k0 += 32) {
        float4 x0 = make_float4(0.f, 0.f, 0.f, 0.f), x1 = x0;
        int grow = row0 + lr;
        if (grow < NN) {
            const float4* xp = (const float4*)(x + (size_t)grow * DIN_ + k0 + lk);
            x0 = xp[0]; x1 = xp[1];
        }
        As[lk + 0][lr] = x0.x; As[lk + 1][lr] = x0.y;
        As[lk + 2][lr] = x0.z; As[lk + 3][lr] = x0.w;
        As[lk + 4][lr] = x1.x; As[lk + 5][lr] = x1.y;
        As[lk + 6][lr] = x1.z; As[lk + 7][lr] = x1.w;
        const float4* wp = (const float4*)(w + (size_t)(k0 + wk) * HD_ + col0 + wn);
        float4 w0 = wp[0], w1 = wp[1];
        Bs[wk][wn + 0] = w0.x; Bs[wk][wn + 1] = w0.y;
        Bs[wk][wn + 2] = w0.z; Bs[wk][wn + 3] = w0.w;
        Bs[wk][wn + 4] = w1.x; Bs[wk][wn + 5] = w1.y;
        Bs[wk][wn + 6] = w1.z; Bs[wk][wn + 7] = w1.w;
        __syncthreads();
#pragma unroll
        for (int kk = 0; kk < 32; kk++) {
            float4 a = *(const float4*)&As[kk][ty * 4];
            float4 b = *(const float4*)&Bs[kk][tx * 4];
            acc[0][0] += a.x * b.x; acc[0][1] += a.x * b.y; acc[0][2] += a.x * b.z; acc[0][3] += a.x * b.w;
            acc[1][0] += a.y * b.x; acc[1][1] += a.y * b.y; acc[1][2] += a.y * b.z; acc[1][3] += a.y * b.w;
            acc[2][0] += a.z * b.x; acc[2][1] += a.z * b.y; acc[2][2] += a.z * b.z; acc[2][3] += a.z * b.w;
            acc[3][0] += a.w * b.x; acc[3][1] += a.w * b.y; acc[3][2] += a.w * b.z; acc[3][3] += a.w * b.w;
        }
        __syncthreads();
    }
#pragma unroll
    for (int i = 0; i < 4; i++) {
        int r = row0 + ty * 4 + i;
        if (r < NN) {
            float4 v = make_float4(acc[i][0], acc[i][1], acc[i][2], acc[i][3]);
            *(float4*)(hfeat + (size_t)r * HD_ + col0 + tx * 4) = v;
        }
    }
}

// ---------------- attention scores a_s, a_d ----------------
__global__ __launch_bounds__(256) void attn_scores(const float* __restrict__ hfeat,
                                                   const float* __restrict__ phi,
                                                   float* __restrict__ a_s,
                                                   float* __restrict__ a_d) {
    int wv = threadIdx.x >> 6, lane = threadIdx.x & 63;
    int n = blockIdx.x * 4 + wv;
    if (n >= NN) return;
    int h = lane >> 4;
    int d0 = (lane & 15) * 4;
    float4 hv = *(const float4*)(hfeat + (size_t)n * HD_ + h * DH_ + d0);
    float ss = 0.f, sd = 0.f;
#pragma unroll
    for (int i = 0; i < 4; i++) {
        float hvv = (i == 0) ? hv.x : (i == 1) ? hv.y : (i == 2) ? hv.z : hv.w;
        float ps = phi[h * 128 + d0 + i];
        float pd = phi[h * 128 + 64 + d0 + i];
        ss += hvv * ps;
        sd += hvv * pd;
    }
#pragma unroll
    for (int o = 1; o < 16; o <<= 1) {
        ss += __shfl_xor(ss, o);
        sd += __shfl_xor(sd, o);
    }
    if ((lane & 15) == 0) {
        a_s[n * 4 + h] = ss;
        a_d[n * 4 + h] = sd;
    }
}

// ---------------- CSR build ----------------
__global__ void hist_deg(const int* __restrict__ src, int* __restrict__ deg) {
    int e = blockIdx.x * 256 + threadIdx.x;
    if (e < EE) atomicAdd(&deg[src[e]], 1);
}

__global__ __launch_bounds__(1024) void scan_off(const int* __restrict__ deg, int* __restrict__ offs) {
    __shared__ int wsum[16];
    int t = threadIdx.x, lane = t & 63, w = t >> 6;
    int running = 0;
    for (int base = 0; base < NN; base += 1024) {
        int i = base + t;
        int v = (i < NN) ? deg[i] : 0;
        int incl = v;
#pragma unroll
        for (int o = 1; o < 64; o <<= 1) {
            int u = __shfl_up(incl, o);
            if (lane >= o) incl += u;
        }
        if (lane == 63) wsum[w] = incl;
        __syncthreads();
        int woff = 0, total = 0;
#pragma unroll
        for (int j = 0; j < 16; j++) {
            int s = wsum[j];
            if (j < w) woff += s;
            total += s;
        }
        if (i < NN) offs[i] = running + woff + incl - v;
        running += total;
        __syncthreads();
    }
    if (t == 0) offs[NN] = running;
}

// fill CSR slots with dst AND precomputed sigmoid weights (kills 2 levels of
// indirection in the gather hot loop)
__global__ void fill_edges(const int* __restrict__ src, const int* __restrict__ dstA,
                           const int* __restrict__ offs, int* __restrict__ cursor,
                           const float* __restrict__ a_s, const float* __restrict__ a_d,
                           int* __restrict__ edge_dst, float4* __restrict__ edge_w) {
    int e = blockIdx.x * 256 + threadIdx.x;
    if (e >= EE) return;
    int s = src[e], d = dstA[e];
    int p = offs[s] + atomicAdd(&cursor[s], 1);
    edge_dst[p] = d;
    float4 as4 = *(const float4*)(a_s + (size_t)s * 4);
    float4 ad4 = *(const float4*)(a_d + (size_t)d * 4);
    float4 w;
    w.x = sigm(leaky(as4.x + ad4.x));
    w.y = sigm(leaky(as4.y + ad4.y));
    w.z = sigm(leaky(as4.z + ad4.z));
    w.w = sigm(leaky(as4.w + ad4.w));
    edge_w[p] = w;
}

// ---------------- aggregation: one wave per node, pure gather ----------------
// lane covers dims [4*lane, 4*lane+4): single dwordx4 per edge per lane.
// No LDS -> high occupancy; 4x edge unroll -> 12 loads in flight.
__global__ __launch_bounds__(256) void agg_kernel(const float* __restrict__ hfeat,
                                                  const int* __restrict__ offs,
                                                  const int* __restrict__ edge_dst,
                                                  const float4* __restrict__ edge_w,
                                                  float* __restrict__ aggG) {
    int wv = threadIdx.x >> 6, lane = threadIdx.x & 63;
    int n = blockIdx.x * 4 + wv;   // grid 12500*4 == 50000
    int e0 = offs[n], e1 = offs[n + 1];
    int hsel = lane >> 4;          // which head this lane's 4 dims belong to
    float4 acc = make_float4(0.f, 0.f, 0.f, 0.f);
    const float* hbase = hfeat + (size_t)lane * 4;

    int i = e0;
    for (; i + 4 <= e1; i += 4) {
        int d0 = edge_dst[i], d1 = edge_dst[i + 1], d2 = edge_dst[i + 2], d3 = edge_dst[i + 3];
        float4 w0 = edge_w[i], w1 = edge_w[i + 1], w2 = edge_w[i + 2], w3 = edge_w[i + 3];
        float4 h0 = *(const float4*)(hbase + (size_t)d0 * HD_);
        float4 h1 = *(const float4*)(hbase + (size_t)d1 * HD_);
        float4 h2 = *(const float4*)(hbase + (size_t)d2 * HD_);
        float4 h3 = *(const float4*)(hbase + (size_t)d3 * HD_);
        float s0 = hsel == 0 ? w0.x : hsel == 1 ? w0.y : hsel == 2 ? w0.z : w0.w;
        float s1 = hsel == 0 ? w1.x : hsel == 1 ? w1.y : hsel == 2 ? w1.z : w1.w;
        float s2 = hsel == 0 ? w2.x : hsel == 1 ? w2.y : hsel == 2 ? w2.z : w2.w;
        float s3 = hsel == 0 ? w3.x : hsel == 1 ? w3.y : hsel == 2 ? w3.z : w3.w;
        acc.x += h0.x * s0; acc.y += h0.y * s0; acc.z += h0.z * s0; acc.w += h0.w * s0;
        acc.x += h1.x * s1; acc.y += h1.y * s1; acc.z += h1.z * s1; acc.w += h1.w * s1;
        acc.x += h2.x * s2; acc.y += h2.y * s2; acc.z += h2.z * s2; acc.w += h2.w * s2;
        acc.x += h3.x * s3; acc.y += h3.y * s3; acc.z += h3.z * s3; acc.w += h3.w * s3;
    }
    for (; i < e1; i++) {
        int d = edge_dst[i];
        float4 w4 = edge_w[i];
        float4 hv = *(const float4*)(hbase + (size_t)d * HD_);
        float s = hsel == 0 ? w4.x : hsel == 1 ? w4.y : hsel == 2 ? w4.z : w4.w;
        acc.x += hv.x * s; acc.y += hv.y * s; acc.z += hv.z * s; acc.w += hv.w * s;
    }
    *(float4*)(aggG + (size_t)n * HD_ + lane * 4) = acc;
}

// ---------------- MLP + softmax + group accumulate ----------------
// 64 nodes per block, 256 threads. Stage 1: z1 = leaky(agg@W1+b1) as a tiled
// GEMM with W1 chunks in LDS (kills the per-node W1 re-read). Stage 2: per-node
// thread computes z@W2, softmax, preds, group atomics.
__global__ __launch_bounds__(256) void mlp_kernel(const float* __restrict__ aggG,
                                                  const float* __restrict__ W1,
                                                  const float* __restrict__ b1,
                                                  const float* __restrict__ W2,
                                                  const float* __restrict__ b2,
                                                  const int* __restrict__ batch,
                                                  float* __restrict__ gsum,
                                                  float* __restrict__ gcnt,
                                                  float* __restrict__ out) {
    __shared__ float As[64][68];   // [k][m]
    __shared__ float Bs[64][68];   // [k][n]
    __shared__ float z1s[64][68];  // [m][n]
    const int tid = threadIdx.x;
    const int n0 = blockIdx.x * 64;
    const int tx = tid & 15, ty = tid >> 4;
    const int lm = tid >> 2, lk = (tid & 3) * 16;  // A loader: row m=lm, 16 k's
    const int wk = tid >> 2, wn = (tid & 3) * 16;  // B loader: k=wk, 16 n's

    float acc[4][4] = {};

    for (int k0 = 0; k0 < 256; k0 += 64) {
        // stage agg tile (64 m x 64 k), transposed to [k][m]
        int grow = n0 + lm;
#pragma unroll
        for (int j = 0; j < 4; j++) {
            float4 v = make_float4(0.f, 0.f, 0.f, 0.f);
            if (grow < NN) v = *(const float4*)(aggG + (size_t)grow * HD_ + k0 + lk + j * 4);
            As[lk + j * 4 + 0][lm] = v.x;
            As[lk + j * 4 + 1][lm] = v.y;
            As[lk + j * 4 + 2][lm] = v.z;
            As[lk + j * 4 + 3][lm] = v.w;
        }
        // stage W1 tile (64 k x 64 n)
#pragma unroll
        for (int j = 0; j < 4; j++) {
            float4 v = *(const float4*)(W1 + (size_t)(k0 + wk) * 64 + wn + j * 4);
            Bs[wk][wn + j * 4 + 0] = v.x;
            Bs[wk][wn + j * 4 + 1] = v.y;
            Bs[wk][wn + j * 4 + 2] = v.z;
            Bs[wk][wn + j * 4 + 3] = v.w;
        }
        __syncthreads();
#pragma unroll
        for (int kk = 0; kk < 64; kk++) {
            float4 a = *(const float4*)&As[kk][ty * 4];
            float4 b = *(const float4*)&Bs[kk][tx * 4];
            acc[0][0] += a.x * b.x; acc[0][1] += a.x * b.y; acc[0][2] += a.x * b.z; acc[0][3] += a.x * b.w;
            acc[1][0] += a.y * b.x; acc[1][1] += a.y * b.y; acc[1][2] += a.y * b.z; acc[1][3] += a.y * b.w;
            acc[2][0] += a.z * b.x; acc[2][1] += a.z * b.y; acc[2][2] += a.z * b.z; acc[2][3] += a.z * b.w;
            acc[3][0] += a.w * b.x; acc[3][1] += a.w * b.y; acc[3][2] += a.w * b.z; acc[3][3] += a.w * b.w;
        }
        __syncthreads();
    }
    // z1 = leaky(acc + b1), into LDS
    float4 bb = *(const float4*)(b1 + tx * 4);
#pragma unroll
    for (int i = 0; i < 4; i++) {
        z1s[ty * 4 + i][tx * 4 + 0] = leaky(acc[i][0] + bb.x);
        z1s[ty * 4 + i][tx * 4 + 1] = leaky(acc[i][1] + bb.y);
        z1s[ty * 4 + i][tx * 4 + 2] = leaky(acc[i][2] + bb.z);
        z1s[ty * 4 + i][tx * 4 + 3] = leaky(acc[i][3] + bb.w);
    }
    __syncthreads();

    // stage 2: one thread per node
    if (tid < 64) {
        int n = n0 + tid;
        if (n < NN) {
            float zc[NC_];
#pragma unroll
            for (int c = 0; c < NC_; c++) zc[c] = b2[c];
            for (int k = 0; k < 64; k += 4) {
                float4 z4 = *(const float4*)&z1s[tid][k];
#pragma unroll
                for (int j = 0; j < 4; j++) {
                    float zv = (j == 0) ? z4.x : (j == 1) ? z4.y : (j == 2) ? z4.z : z4.w;
#pragma unroll
                    for (int c = 0; c < NC_; c++) zc[c] += zv * W2[(k + j) * NC_ + c];
                }
            }
            float m = zc[0];
#pragma unroll
            for (int c = 1; c < NC_; c++) m = fmaxf(m, zc[c]);
            float ssum = 0.f;
#pragma unroll
            for (int c = 0; c < NC_; c++) { zc[c] = __expf(zc[c] - m) + EPS_; ssum += zc[c]; }
            float inv = 1.f / ssum;
            int g = batch[n];
#pragma unroll
            for (int c = 0; c < NC_; c++) {
                float pr = zc[c] * inv;
                out[1000 + (size_t)n * NC_ + c] = pr;
                atomicAdd(&gsum[g * NC_ + c], pr);
            }
            atomicAdd(&gcnt[g], 1.0f);
        }
    }
}

// ---------------- finalize log(yp) ----------------
__global__ void finalize(const float* __restrict__ gsum, const float* __restrict__ gcnt,
                         float* __restrict__ out) {
    int i = blockIdx.x * 256 + threadIdx.x;
    if (i < NG_ * NC_) {
        int g = i / NC_;
        out[i] = __logf(gsum[i] / gcnt[g]);
    }
}

extern "C" void kernel_launch(void* const* d_in, const int* in_sizes, int n_in,
                              void* d_out, int out_size, void* d_ws, size_t ws_size,
                              hipStream_t stream) {
    const float* x      = (const float*)d_in[0];
    const int*   midx   = (const int*)d_in[1];
    const int*   batch  = (const int*)d_in[2];
    const float* W_feat = (const float*)d_in[3];
    const float* phi    = (const float*)d_in[4];
    const float* W1     = (const float*)d_in[5];
    const float* b1     = (const float*)d_in[6];
    const float* W2     = (const float*)d_in[7];
    const float* b2     = (const float*)d_in[8];
    const int* src = midx;
    const int* dst = midx + EE;
    float* out = (float*)d_out;

    char* p = (char*)d_ws;
    auto alloc = [&](size_t bytes) { void* r = (void*)p; p += (bytes + 255) & ~(size_t)255; return r; };
    float*  hfeat    = (float*)alloc((size_t)NN * HD_ * 4);
    float*  aggG     = (float*)alloc((size_t)NN * HD_ * 4);
    float4* edge_w   = (float4*)alloc((size_t)EE * 16);
    int*    edge_dst = (int*)alloc((size_t)EE * 4);
    float*  a_s      = (float*)alloc((size_t)NN * 4 * 4);
    float*  a_d      = (float*)alloc((size_t)NN * 4 * 4);
    int*    deg      = (int*)alloc((size_t)NN * 4);
    int*    offs     = (int*)alloc((size_t)(NN + 1) * 4);
    int*    cursor   = (int*)alloc((size_t)NN * 4);
    float*  gsum     = (float*)alloc((size_t)NG_ * NC_ * 4);
    float*  gcnt     = (float*)alloc((size_t)NG_ * 4);

    init_zero<<<(NN + 255) / 256, 256, 0, stream>>>(deg, cursor, gsum, gcnt);
    gemm_h<<<dim3((NN + 63) / 64, HD_ / 64), 256, 0, stream>>>(x, W_feat, hfeat);
    attn_scores<<<(NN + 3) / 4, 256, 0, stream>>>(hfeat, phi, a_s, a_d);
    hist_deg<<<(EE + 255) / 256, 256, 0, stream>>>(src, deg);
    scan_off<<<1, 1024, 0, stream>>>(deg, offs);
    fill_edges<<<(EE + 255) / 256, 256, 0, stream>>>(src, dst, offs, cursor, a_s, a_d,
                                                     edge_dst, edge_w);
    agg_kernel<<<NN / 4, 256, 0, stream>>>(hfeat, offs, edge_dst, edge_w, aggG);
    mlp_kernel<<<(NN + 63) / 64, 256, 0, stream>>>(aggG, W1, b1, W2, b2, batch,
                                                   gsum, gcnt, out);
    finalize<<<4, 256, 0, stream>>>(gsum, gcnt, out);
}

// Round 4
// 505.747 us; speedup vs baseline: 1.5655x; 1.5655x over previous
//
#include <hip/hip_runtime.h>
#include <hip/hip_bf16.h>
#include <cstdint>

#define NN   50000
#define EE   800000
#define DIN_ 256
#define HD_  256     // H*DH
#define DH_  64
#define NH_  4
#define NC_  10
#define NG_  100
#define EPS_ 1e-4f
#define SLOPE_ 0.01f

__device__ __forceinline__ float leaky(float x) { return x >= 0.f ? x : SLOPE_ * x; }
__device__ __forceinline__ float sigm(float x)  { return 1.f / (1.f + __expf(-x)); }

// ---------------- init: zero deg/cursor ----------------
__global__ void init_zero(int* deg, int* cursor) {
    int i = blockIdx.x * 256 + threadIdx.x;
    if (i < NN) { deg[i] = 0; cursor[i] = 0; }
}

// ---------------- GEMM: h = x @ W_feat  (fp32) ----------------
__global__ __launch_bounds__(256) void gemm_h(const float* __restrict__ x,
                                              const float* __restrict__ w,
                                              float* __restrict__ hfeat) {
    __shared__ float As[32][68];
    __shared__ float Bs[32][68];
    const int tid = threadIdx.x;
    const int row0 = blockIdx.x * 64;
    const int col0 = blockIdx.y * 64;
    const int tx = tid & 15, ty = tid >> 4;
    const int lr = tid >> 2, lk = (tid & 3) * 8;
    const int wk = tid >> 3, wn = (tid & 7) * 8;

    float acc[4][4] = {};

    for (int k0 = 0; k0 < DIN_; k0 += 32) {
        float4 x0 = make_float4(0.f, 0.f, 0.f, 0.f), x1 = x0;
        int grow = row0 + lr;
        if (grow < NN) {
            const float4* xp = (const float4*)(x + (size_t)grow * DIN_ + k0 + lk);
            x0 = xp[0]; x1 = xp[1];
        }
        As[lk + 0][lr] = x0.x; As[lk + 1][lr] = x0.y;
        As[lk + 2][lr] = x0.z; As[lk + 3][lr] = x0.w;
        As[lk + 4][lr] = x1.x; As[lk + 5][lr] = x1.y;
        As[lk + 6][lr] = x1.z; As[lk + 7][lr] = x1.w;
        const float4* wp = (const float4*)(w + (size_t)(k0 + wk) * HD_ + col0 + wn);
        float4 w0 = wp[0], w1 = wp[1];
        Bs[wk][wn + 0] = w0.x; Bs[wk][wn + 1] = w0.y;
        Bs[wk][wn + 2] = w0.z; Bs[wk][wn + 3] = w0.w;
        Bs[wk][wn + 4] = w1.x; Bs[wk][wn + 5] = w1.y;
        Bs[wk][wn + 6] = w1.z; Bs[wk][wn + 7] = w1.w;
        __syncthreads();
#pragma unroll
        for (int kk = 0; kk < 32; kk++) {
            float4 a = *(const float4*)&As[kk][ty * 4];
            float4 b = *(const float4*)&Bs[kk][tx * 4];
            acc[0][0] += a.x * b.x; acc[0][1] += a.x * b.y; acc[0][2] += a.x * b.z; acc[0][3] += a.x * b.w;
            acc[1][0] += a.y * b.x; acc[1][1] += a.y * b.y; acc[1][2] += a.y * b.z; acc[1][3] += a.y * b.w;
            acc[2][0] += a.z * b.x; acc[2][1] += a.z * b.y; acc[2][2] += a.z * b.z; acc[2][3] += a.z * b.w;
            acc[3][0] += a.w * b.x; acc[3][1] += a.w * b.y; acc[3][2] += a.w * b.z; acc[3][3] += a.w * b.w;
        }
        __syncthreads();
    }
#pragma unroll
    for (int i = 0; i < 4; i++) {
        int r = row0 + ty * 4 + i;
        if (r < NN) {
            float4 v = make_float4(acc[i][0], acc[i][1], acc[i][2], acc[i][3]);
            *(float4*)(hfeat + (size_t)r * HD_ + col0 + tx * 4) = v;
        }
    }
}

// ---------------- attention scores a_s, a_d ----------------
__global__ __launch_bounds__(256) void attn_scores(const float* __restrict__ hfeat,
                                                   const float* __restrict__ phi,
                                                   float* __restrict__ a_s,
                                                   float* __restrict__ a_d) {
    int wv = threadIdx.x >> 6, lane = threadIdx.x & 63;
    int n = blockIdx.x * 4 + wv;
    if (n >= NN) return;
    int h = lane >> 4;
    int d0 = (lane & 15) * 4;
    float4 hv = *(const float4*)(hfeat + (size_t)n * HD_ + h * DH_ + d0);
    float ss = 0.f, sd = 0.f;
#pragma unroll
    for (int i = 0; i < 4; i++) {
        float hvv = (i == 0) ? hv.x : (i == 1) ? hv.y : (i == 2) ? hv.z : hv.w;
        float ps = phi[h * 128 + d0 + i];
        float pd = phi[h * 128 + 64 + d0 + i];
        ss += hvv * ps;
        sd += hvv * pd;
    }
#pragma unroll
    for (int o = 1; o < 16; o <<= 1) {
        ss += __shfl_xor(ss, o);
        sd += __shfl_xor(sd, o);
    }
    if ((lane & 15) == 0) {
        a_s[n * 4 + h] = ss;
        a_d[n * 4 + h] = sd;
    }
}

// ---------------- CSR build ----------------
__global__ void hist_deg(const int* __restrict__ src, int* __restrict__ deg) {
    int e = blockIdx.x * 256 + threadIdx.x;
    if (e < EE) atomicAdd(&deg[src[e]], 1);
}

__global__ __launch_bounds__(1024) void scan_off(const int* __restrict__ deg, int* __restrict__ offs) {
    __shared__ int wsum[16];
    int t = threadIdx.x, lane = t & 63, w = t >> 6;
    int running = 0;
    for (int base = 0; base < NN; base += 1024) {
        int i = base + t;
        int v = (i < NN) ? deg[i] : 0;
        int incl = v;
#pragma unroll
        for (int o = 1; o < 64; o <<= 1) {
            int u = __shfl_up(incl, o);
            if (lane >= o) incl += u;
        }
        if (lane == 63) wsum[w] = incl;
        __syncthreads();
        int woff = 0, total = 0;
#pragma unroll
        for (int j = 0; j < 16; j++) {
            int s = wsum[j];
            if (j < w) woff += s;
            total += s;
        }
        if (i < NN) offs[i] = running + woff + incl - v;
        running += total;
        __syncthreads();
    }
    if (t == 0) offs[NN] = running;
}

// fill CSR slots with dst AND precomputed sigmoid weights
__global__ void fill_edges(const int* __restrict__ src, const int* __restrict__ dstA,
                           const int* __restrict__ offs, int* __restrict__ cursor,
                           const float* __restrict__ a_s, const float* __restrict__ a_d,
                           int* __restrict__ edge_dst, float4* __restrict__ edge_w) {
    int e = blockIdx.x * 256 + threadIdx.x;
    if (e >= EE) return;
    int s = src[e], d = dstA[e];
    int p = offs[s] + atomicAdd(&cursor[s], 1);
    edge_dst[p] = d;
    float4 as4 = *(const float4*)(a_s + (size_t)s * 4);
    float4 ad4 = *(const float4*)(a_d + (size_t)d * 4);
    float4 w;
    w.x = sigm(leaky(as4.x + ad4.x));
    w.y = sigm(leaky(as4.y + ad4.y));
    w.z = sigm(leaky(as4.z + ad4.z));
    w.w = sigm(leaky(as4.w + ad4.w));
    edge_w[p] = w;
}

// ---------------- aggregation: one wave per node, pure gather ----------------
__global__ __launch_bounds__(256) void agg_kernel(const float* __restrict__ hfeat,
                                                  const int* __restrict__ offs,
                                                  const int* __restrict__ edge_dst,
                                                  const float4* __restrict__ edge_w,
                                                  float* __restrict__ aggG) {
    int wv = threadIdx.x >> 6, lane = threadIdx.x & 63;
    int n = blockIdx.x * 4 + wv;   // grid 12500*4 == 50000
    int e0 = offs[n], e1 = offs[n + 1];
    int hsel = lane >> 4;
    float4 acc = make_float4(0.f, 0.f, 0.f, 0.f);
    const float* hbase = hfeat + (size_t)lane * 4;

    int i = e0;
    for (; i + 4 <= e1; i += 4) {
        int d0 = edge_dst[i], d1 = edge_dst[i + 1], d2 = edge_dst[i + 2], d3 = edge_dst[i + 3];
        float4 w0 = edge_w[i], w1 = edge_w[i + 1], w2 = edge_w[i + 2], w3 = edge_w[i + 3];
        float4 h0 = *(const float4*)(hbase + (size_t)d0 * HD_);
        float4 h1 = *(const float4*)(hbase + (size_t)d1 * HD_);
        float4 h2 = *(const float4*)(hbase + (size_t)d2 * HD_);
        float4 h3 = *(const float4*)(hbase + (size_t)d3 * HD_);
        float s0 = hsel == 0 ? w0.x : hsel == 1 ? w0.y : hsel == 2 ? w0.z : w0.w;
        float s1 = hsel == 0 ? w1.x : hsel == 1 ? w1.y : hsel == 2 ? w1.z : w1.w;
        float s2 = hsel == 0 ? w2.x : hsel == 1 ? w2.y : hsel == 2 ? w2.z : w2.w;
        float s3 = hsel == 0 ? w3.x : hsel == 1 ? w3.y : hsel == 2 ? w3.z : w3.w;
        acc.x += h0.x * s0; acc.y += h0.y * s0; acc.z += h0.z * s0; acc.w += h0.w * s0;
        acc.x += h1.x * s1; acc.y += h1.y * s1; acc.z += h1.z * s1; acc.w += h1.w * s1;
        acc.x += h2.x * s2; acc.y += h2.y * s2; acc.z += h2.z * s2; acc.w += h2.w * s2;
        acc.x += h3.x * s3; acc.y += h3.y * s3; acc.z += h3.z * s3; acc.w += h3.w * s3;
    }
    for (; i < e1; i++) {
        int d = edge_dst[i];
        float4 w4 = edge_w[i];
        float4 hv = *(const float4*)(hbase + (size_t)d * HD_);
        float s = hsel == 0 ? w4.x : hsel == 1 ? w4.y : hsel == 2 ? w4.z : w4.w;
        acc.x += hv.x * s; acc.y += hv.y * s; acc.z += hv.z * s; acc.w += hv.w * s;
    }
    *(float4*)(aggG + (size_t)n * HD_ + lane * 4) = acc;
}

// ---------------- MLP + softmax: writes preds only (NO atomics) ----------------
__global__ __launch_bounds__(256) void mlp_kernel(const float* __restrict__ aggG,
                                                  const float* __restrict__ W1,
                                                  const float* __restrict__ b1,
                                                  const float* __restrict__ W2,
                                                  const float* __restrict__ b2,
                                                  float* __restrict__ out) {
    __shared__ float As[64][68];   // [k][m]
    __shared__ float Bs[64][68];   // [k][n]
    __shared__ float z1t[64][68];  // [hidden][node] (transposed: conflict-free stage-2 reads)
    const int tid = threadIdx.x;
    const int n0 = blockIdx.x * 64;
    const int tx = tid & 15, ty = tid >> 4;
    const int lm = tid >> 2, lk = (tid & 3) * 16;
    const int wk = tid >> 2, wn = (tid & 3) * 16;

    float acc[4][4] = {};

    for (int k0 = 0; k0 < 256; k0 += 64) {
        int grow = n0 + lm;
#pragma unroll
        for (int j = 0; j < 4; j++) {
            float4 v = make_float4(0.f, 0.f, 0.f, 0.f);
            if (grow < NN) v = *(const float4*)(aggG + (size_t)grow * HD_ + k0 + lk + j * 4);
            As[lk + j * 4 + 0][lm] = v.x;
            As[lk + j * 4 + 1][lm] = v.y;
            As[lk + j * 4 + 2][lm] = v.z;
            As[lk + j * 4 + 3][lm] = v.w;
        }
#pragma unroll
        for (int j = 0; j < 4; j++) {
            float4 v = *(const float4*)(W1 + (size_t)(k0 + wk) * 64 + wn + j * 4);
            Bs[wk][wn + j * 4 + 0] = v.x;
            Bs[wk][wn + j * 4 + 1] = v.y;
            Bs[wk][wn + j * 4 + 2] = v.z;
            Bs[wk][wn + j * 4 + 3] = v.w;
        }
        __syncthreads();
#pragma unroll
        for (int kk = 0; kk < 64; kk++) {
            float4 a = *(const float4*)&As[kk][ty * 4];
            float4 b = *(const float4*)&Bs[kk][tx * 4];
            acc[0][0] += a.x * b.x; acc[0][1] += a.x * b.y; acc[0][2] += a.x * b.z; acc[0][3] += a.x * b.w;
            acc[1][0] += a.y * b.x; acc[1][1] += a.y * b.y; acc[1][2] += a.y * b.z; acc[1][3] += a.y * b.w;
            acc[2][0] += a.z * b.x; acc[2][1] += a.z * b.y; acc[2][2] += a.z * b.z; acc[2][3] += a.z * b.w;
            acc[3][0] += a.w * b.x; acc[3][1] += a.w * b.y; acc[3][2] += a.w * b.z; acc[3][3] += a.w * b.w;
        }
        __syncthreads();
    }
    // z1t[hidden][node] = leaky(acc + b1)
    float4 bb = *(const float4*)(b1 + tx * 4);
#pragma unroll
    for (int i = 0; i < 4; i++) {
        z1t[tx * 4 + 0][ty * 4 + i] = leaky(acc[i][0] + bb.x);
        z1t[tx * 4 + 1][ty * 4 + i] = leaky(acc[i][1] + bb.y);
        z1t[tx * 4 + 2][ty * 4 + i] = leaky(acc[i][2] + bb.z);
        z1t[tx * 4 + 3][ty * 4 + i] = leaky(acc[i][3] + bb.w);
    }
    __syncthreads();

    // stage 2: one thread per node
    if (tid < 64) {
        int n = n0 + tid;
        if (n < NN) {
            float zc[NC_];
#pragma unroll
            for (int c = 0; c < NC_; c++) zc[c] = b2[c];
            for (int k = 0; k < 64; k++) {
                float zv = z1t[k][tid];
#pragma unroll
                for (int c = 0; c < NC_; c++) zc[c] += zv * W2[k * NC_ + c];
            }
            float m = zc[0];
#pragma unroll
            for (int c = 1; c < NC_; c++) m = fmaxf(m, zc[c]);
            float ssum = 0.f;
#pragma unroll
            for (int c = 0; c < NC_; c++) { zc[c] = __expf(zc[c] - m) + EPS_; ssum += zc[c]; }
            float inv = 1.f / ssum;
#pragma unroll
            for (int c = 0; c < NC_; c++) out[1000 + (size_t)n * NC_ + c] = zc[c] * inv;
        }
    }
}

// ---------------- group boundaries (batch is sorted) ----------------
__global__ void gstart_kernel(const int* __restrict__ batch, int* __restrict__ gstart) {
    int n = blockIdx.x * 256 + threadIdx.x;
    if (n >= NN) return;
    int b = batch[n];
    int bp = (n == 0) ? -1 : batch[n - 1];
    for (int g = bp + 1; g <= b; g++) gstart[g] = n;
    if (n == NN - 1) {
        for (int g = b + 1; g <= NG_; g++) gstart[g] = NN;
    }
}

// ---------------- group mean + log: one block per group ----------------
__global__ __launch_bounds__(256) void group_mean(const float* __restrict__ preds,
                                                  const int* __restrict__ gstart,
                                                  float* __restrict__ out) {
    __shared__ float red[16][16];
    int g = blockIdx.x;
    int t = threadIdx.x;
    int c = t & 15, chunk = t >> 4;
    int gs = gstart[g], ge = gstart[g + 1];
    float s = 0.f;
    if (c < NC_) {
        for (int n = gs + chunk; n < ge; n += 16) s += preds[(size_t)n * NC_ + c];
    }
    red[chunk][c] = s;
    __syncthreads();
    if (t < NC_) {
        float tot = 0.f;
#pragma unroll
        for (int j = 0; j < 16; j++) tot += red[j][t];
        out[g * NC_ + t] = __logf(tot / (float)(ge - gs));
    }
}

extern "C" void kernel_launch(void* const* d_in, const int* in_sizes, int n_in,
                              void* d_out, int out_size, void* d_ws, size_t ws_size,
                              hipStream_t stream) {
    const float* x      = (const float*)d_in[0];
    const int*   midx   = (const int*)d_in[1];
    const int*   batch  = (const int*)d_in[2];
    const float* W_feat = (const float*)d_in[3];
    const float* phi    = (const float*)d_in[4];
    const float* W1     = (const float*)d_in[5];
    const float* b1     = (const float*)d_in[6];
    const float* W2     = (const float*)d_in[7];
    const float* b2     = (const float*)d_in[8];
    const int* src = midx;
    const int* dst = midx + EE;
    float* out = (float*)d_out;

    char* p = (char*)d_ws;
    auto alloc = [&](size_t bytes) { void* r = (void*)p; p += (bytes + 255) & ~(size_t)255; return r; };
    float*  hfeat    = (float*)alloc((size_t)NN * HD_ * 4);
    float*  aggG     = (float*)alloc((size_t)NN * HD_ * 4);
    float4* edge_w   = (float4*)alloc((size_t)EE * 16);
    int*    edge_dst = (int*)alloc((size_t)EE * 4);
    float*  a_s      = (float*)alloc((size_t)NN * 4 * 4);
    float*  a_d      = (float*)alloc((size_t)NN * 4 * 4);
    int*    deg      = (int*)alloc((size_t)NN * 4);
    int*    offs     = (int*)alloc((size_t)(NN + 1) * 4);
    int*    cursor   = (int*)alloc((size_t)NN * 4);
    int*    gstart   = (int*)alloc((size_t)(NG_ + 1) * 4);

    init_zero<<<(NN + 255) / 256, 256, 0, stream>>>(deg, cursor);
    gemm_h<<<dim3((NN + 63) / 64, HD_ / 64), 256, 0, stream>>>(x, W_feat, hfeat);
    attn_scores<<<(NN + 3) / 4, 256, 0, stream>>>(hfeat, phi, a_s, a_d);
    hist_deg<<<(EE + 255) / 256, 256, 0, stream>>>(src, deg);
    scan_off<<<1, 1024, 0, stream>>>(deg, offs);
    fill_edges<<<(EE + 255) / 256, 256, 0, stream>>>(src, dst, offs, cursor, a_s, a_d,
                                                     edge_dst, edge_w);
    agg_kernel<<<NN / 4, 256, 0, stream>>>(hfeat, offs, edge_dst, edge_w, aggG);
    mlp_kernel<<<(NN + 63) / 64, 256, 0, stream>>>(aggG, W1, b1, W2, b2, out);
    gstart_kernel<<<(NN + 255) / 256, 256, 0, stream>>>(batch, gstart);
    group_mean<<<NG_, 256, 0, stream>>>(out + 1000, gstart, out);
}

// Round 5
// 379.508 us; speedup vs baseline: 2.0863x; 1.3326x over previous
//
#include <hip/hip_runtime.h>
#include <hip/hip_bf16.h>
#include <cstdint>

#define NN   50000
#define EE   800000
#define DIN_ 256
#define HD_  256     // H*DH
#define DH_  64
#define NH_  4
#define NC_  10
#define NG_  100
#define EPS_ 1e-4f
#define SLOPE_ 0.01f
#define AROW 40      // LDS row stride in ushorts (32 data + 8 pad -> 80B, 16B-aligned, 2-way banks)

typedef unsigned short ushortT;
typedef __attribute__((ext_vector_type(8))) short short8;
typedef __attribute__((ext_vector_type(4))) float f32x4;

__device__ __forceinline__ float leaky(float x) { return x >= 0.f ? x : SLOPE_ * x; }
__device__ __forceinline__ float sigm(float x)  { return 1.f / (1.f + __expf(-x)); }
__device__ __forceinline__ float b2f(ushortT u) { return __uint_as_float(((unsigned)u) << 16); }
__device__ __forceinline__ ushortT f2b(float f) {            // RNE fp32->bf16
    unsigned u = __float_as_uint(f);
    u += 0x7fffu + ((u >> 16) & 1u);
    return (ushortT)(u >> 16);
}

// ---------------- init: zero deg/cursor ----------------
__global__ void init_zero(int* deg, int* cursor) {
    int i = blockIdx.x * 256 + threadIdx.x;
    if (i < NN) { deg[i] = 0; cursor[i] = 0; }
}

// ---------------- prep: W_feat (fp32 [k][n]) -> bf16 transposed [n][k] ----------------
__global__ void prep_w(const float* __restrict__ W, ushortT* __restrict__ wt) {
    int e = blockIdx.x * 256 + threadIdx.x;   // 65536 elements
    if (e < DIN_ * HD_) {
        int k = e >> 8, n = e & 255;
        wt[n * DIN_ + k] = f2b(W[e]);
    }
}

// ---------------- MFMA GEMM: hbf = bf16( x @ W_feat ) ----------------
// 256 threads = 4 waves; block tile 128x128; wave tile 64x64 (4x4 of 16x16x32).
__global__ __launch_bounds__(256) void gemm_h_mfma(const float* __restrict__ x,
                                                   const ushortT* __restrict__ wt,
                                                   ushortT* __restrict__ hbf) {
    __shared__ ushortT A_lds[128 * AROW];   // [m][k] bf16
    __shared__ ushortT B_lds[128 * AROW];   // [n][k] bf16
    const int tid  = threadIdx.x;
    const int wave = tid >> 6, lane = tid & 63;
    const int wm = wave >> 1, wn = wave & 1;
    const int row0 = blockIdx.x * 128;
    const int col0 = blockIdx.y * 128;
    const int q = lane >> 4, l16 = lane & 15;

    f32x4 acc[4][4];
#pragma unroll
    for (int i = 0; i < 4; i++)
#pragma unroll
        for (int j = 0; j < 4; j++) acc[i][j] = (f32x4){0.f, 0.f, 0.f, 0.f};

    const int lm  = tid >> 1;           // 0..127
    const int lko = (tid & 1) * 16;     // 0 or 16

    for (int k0 = 0; k0 < DIN_; k0 += 32) {
        __syncthreads();   // protect LDS from previous iteration's readers
        // ---- stage A: x[row0+lm][k0+lko .. +16) -> bf16 ----
        {
            int gr = row0 + lm;
            float4 a0 = make_float4(0.f,0.f,0.f,0.f), a1 = a0, a2 = a0, a3 = a0;
            if (gr < NN) {
                const float4* xp = (const float4*)(x + (size_t)gr * DIN_ + k0 + lko);
                a0 = xp[0]; a1 = xp[1]; a2 = xp[2]; a3 = xp[3];
            }
            ushortT* ap = &A_lds[lm * AROW + lko];
            *(ushort4*)(ap + 0)  = make_ushort4(f2b(a0.x), f2b(a0.y), f2b(a0.z), f2b(a0.w));
            *(ushort4*)(ap + 4)  = make_ushort4(f2b(a1.x), f2b(a1.y), f2b(a1.z), f2b(a1.w));
            *(ushort4*)(ap + 8)  = make_ushort4(f2b(a2.x), f2b(a2.y), f2b(a2.z), f2b(a2.w));
            *(ushort4*)(ap + 12) = make_ushort4(f2b(a3.x), f2b(a3.y), f2b(a3.z), f2b(a3.w));
        }
        // ---- stage B: wt[col0+lm][k0+lko .. +16) (already bf16, [n][k]) ----
        {
            const uint4* wp = (const uint4*)(wt + (size_t)(col0 + lm) * DIN_ + k0 + lko);
            uint4 b0 = wp[0], b1 = wp[1];
            *(uint4*)&B_lds[lm * AROW + lko + 0] = b0;
            *(uint4*)&B_lds[lm * AROW + lko + 8] = b1;
        }
        __syncthreads();

        short8 af[4], bf[4];
#pragma unroll
        for (int mi = 0; mi < 4; mi++)
            af[mi] = *(const short8*)&A_lds[(wm * 64 + mi * 16 + l16) * AROW + q * 8];
#pragma unroll
        for (int ni = 0; ni < 4; ni++)
            bf[ni] = *(const short8*)&B_lds[(wn * 64 + ni * 16 + l16) * AROW + q * 8];
#pragma unroll
        for (int mi = 0; mi < 4; mi++)
#pragma unroll
            for (int ni = 0; ni < 4; ni++)
                acc[mi][ni] = __builtin_amdgcn_mfma_f32_16x16x32_bf16(af[mi], bf[ni], acc[mi][ni], 0, 0, 0);
    }

    // epilogue: D layout col=lane&15, row=q*4+reg
#pragma unroll
    for (int mi = 0; mi < 4; mi++) {
        int rbase = row0 + wm * 64 + mi * 16 + q * 4;
#pragma unroll
        for (int ni = 0; ni < 4; ni++) {
            int c = col0 + wn * 64 + ni * 16 + l16;
#pragma unroll
            for (int r = 0; r < 4; r++) {
                int gr = rbase + r;
                if (gr < NN) hbf[(size_t)gr * HD_ + c] = f2b(acc[mi][ni][r]);
            }
        }
    }
}

// ---------------- attention scores a_s, a_d (bf16 h) ----------------
__global__ __launch_bounds__(256) void attn_scores(const ushortT* __restrict__ hbf,
                                                   const float* __restrict__ phi,
                                                   float* __restrict__ a_s,
                                                   float* __restrict__ a_d) {
    int wv = threadIdx.x >> 6, lane = threadIdx.x & 63;
    int n = blockIdx.x * 4 + wv;
    if (n >= NN) return;
    int h = lane >> 4;
    int d0 = (lane & 15) * 4;
    ushort4 hv = *(const ushort4*)(hbf + (size_t)n * HD_ + h * DH_ + d0);
    float hw[4] = { b2f(hv.x), b2f(hv.y), b2f(hv.z), b2f(hv.w) };
    float ss = 0.f, sd = 0.f;
#pragma unroll
    for (int i = 0; i < 4; i++) {
        ss += hw[i] * phi[h * 128 + d0 + i];
        sd += hw[i] * phi[h * 128 + 64 + d0 + i];
    }
#pragma unroll
    for (int o = 1; o < 16; o <<= 1) {
        ss += __shfl_xor(ss, o);
        sd += __shfl_xor(sd, o);
    }
    if ((lane & 15) == 0) {
        a_s[n * 4 + h] = ss;
        a_d[n * 4 + h] = sd;
    }
}

// ---------------- CSR build ----------------
__global__ void hist_deg(const int* __restrict__ src, int* __restrict__ deg) {
    int e = blockIdx.x * 256 + threadIdx.x;
    if (e < EE) atomicAdd(&deg[src[e]], 1);
}

__global__ __launch_bounds__(1024) void scan_off(const int* __restrict__ deg, int* __restrict__ offs) {
    __shared__ int wsum[16];
    int t = threadIdx.x, lane = t & 63, w = t >> 6;
    int running = 0;
    for (int base = 0; base < NN; base += 1024) {
        int i = base + t;
        int v = (i < NN) ? deg[i] : 0;
        int incl = v;
#pragma unroll
        for (int o = 1; o < 64; o <<= 1) {
            int u = __shfl_up(incl, o);
            if (lane >= o) incl += u;
        }
        if (lane == 63) wsum[w] = incl;
        __syncthreads();
        int woff = 0, total = 0;
#pragma unroll
        for (int j = 0; j < 16; j++) {
            int s = wsum[j];
            if (j < w) woff += s;
            total += s;
        }
        if (i < NN) offs[i] = running + woff + incl - v;
        running += total;
        __syncthreads();
    }
    if (t == 0) offs[NN] = running;
}

__global__ void fill_edges(const int* __restrict__ src, const int* __restrict__ dstA,
                           const int* __restrict__ offs, int* __restrict__ cursor,
                           const float* __restrict__ a_s, const float* __restrict__ a_d,
                           int* __restrict__ edge_dst, float4* __restrict__ edge_w) {
    int e = blockIdx.x * 256 + threadIdx.x;
    if (e >= EE) return;
    int s = src[e], d = dstA[e];
    int p = offs[s] + atomicAdd(&cursor[s], 1);
    edge_dst[p] = d;
    float4 as4 = *(const float4*)(a_s + (size_t)s * 4);
    float4 ad4 = *(const float4*)(a_d + (size_t)d * 4);
    float4 w;
    w.x = sigm(leaky(as4.x + ad4.x));
    w.y = sigm(leaky(as4.y + ad4.y));
    w.z = sigm(leaky(as4.z + ad4.z));
    w.w = sigm(leaky(as4.w + ad4.w));
    edge_w[p] = w;
}

// ---------------- aggregation: one wave per node, bf16 gather ----------------
__global__ __launch_bounds__(256) void agg_kernel(const ushortT* __restrict__ hbf,
                                                  const int* __restrict__ offs,
                                                  const int* __restrict__ edge_dst,
                                                  const float4* __restrict__ edge_w,
                                                  float* __restrict__ aggG) {
    int wv = threadIdx.x >> 6, lane = threadIdx.x & 63;
    int n = blockIdx.x * 4 + wv;   // grid 12500*4 == 50000
    int e0 = offs[n], e1 = offs[n + 1];
    int hsel = lane >> 4;
    float4 acc = make_float4(0.f, 0.f, 0.f, 0.f);
    const ushortT* hbase = hbf + (size_t)lane * 4;

    int i = e0;
    for (; i + 4 <= e1; i += 4) {
        int d0 = edge_dst[i], d1 = edge_dst[i + 1], d2 = edge_dst[i + 2], d3 = edge_dst[i + 3];
        float4 w0 = edge_w[i], w1 = edge_w[i + 1], w2 = edge_w[i + 2], w3 = edge_w[i + 3];
        ushort4 h0 = *(const ushort4*)(hbase + (size_t)d0 * HD_);
        ushort4 h1 = *(const ushort4*)(hbase + (size_t)d1 * HD_);
        ushort4 h2 = *(const ushort4*)(hbase + (size_t)d2 * HD_);
        ushort4 h3 = *(const ushort4*)(hbase + (size_t)d3 * HD_);
        float s0 = hsel == 0 ? w0.x : hsel == 1 ? w0.y : hsel == 2 ? w0.z : w0.w;
        float s1 = hsel == 0 ? w1.x : hsel == 1 ? w1.y : hsel == 2 ? w1.z : w1.w;
        float s2 = hsel == 0 ? w2.x : hsel == 1 ? w2.y : hsel == 2 ? w2.z : w2.w;
        float s3 = hsel == 0 ? w3.x : hsel == 1 ? w3.y : hsel == 2 ? w3.z : w3.w;
        acc.x += b2f(h0.x) * s0; acc.y += b2f(h0.y) * s0; acc.z += b2f(h0.z) * s0; acc.w += b2f(h0.w) * s0;
        acc.x += b2f(h1.x) * s1; acc.y += b2f(h1.y) * s1; acc.z += b2f(h1.z) * s1; acc.w += b2f(h1.w) * s1;
        acc.x += b2f(h2.x) * s2; acc.y += b2f(h2.y) * s2; acc.z += b2f(h2.z) * s2; acc.w += b2f(h2.w) * s2;
        acc.x += b2f(h3.x) * s3; acc.y += b2f(h3.y) * s3; acc.z += b2f(h3.z) * s3; acc.w += b2f(h3.w) * s3;
    }
    for (; i < e1; i++) {
        int d = edge_dst[i];
        float4 w4 = edge_w[i];
        ushort4 hv = *(const ushort4*)(hbase + (size_t)d * HD_);
        float s = hsel == 0 ? w4.x : hsel == 1 ? w4.y : hsel == 2 ? w4.z : w4.w;
        acc.x += b2f(hv.x) * s; acc.y += b2f(hv.y) * s; acc.z += b2f(hv.z) * s; acc.w += b2f(hv.w) * s;
    }
    *(float4*)(aggG + (size_t)n * HD_ + lane * 4) = acc;
}

// ---------------- MLP + softmax: writes preds only (NO atomics) ----------------
__global__ __launch_bounds__(256) void mlp_kernel(const float* __restrict__ aggG,
                                                  const float* __restrict__ W1,
                                                  const float* __restrict__ b1,
                                                  const float* __restrict__ W2,
                                                  const float* __restrict__ b2,
                                                  float* __restrict__ out) {
    __shared__ float As[64][68];
    __shared__ float Bs[64][68];
    __shared__ float z1t[64][68];
    const int tid = threadIdx.x;
    const int n0 = blockIdx.x * 64;
    const int tx = tid & 15, ty = tid >> 4;
    const int lm = tid >> 2, lk = (tid & 3) * 16;
    const int wk = tid >> 2, wn = (tid & 3) * 16;

    float acc[4][4] = {};

    for (int k0 = 0; k0 < 256; k0 += 64) {
        int grow = n0 + lm;
#pragma unroll
        for (int j = 0; j < 4; j++) {
            float4 v = make_float4(0.f, 0.f, 0.f, 0.f);
            if (grow < NN) v = *(const float4*)(aggG + (size_t)grow * HD_ + k0 + lk + j * 4);
            As[lk + j * 4 + 0][lm] = v.x;
            As[lk + j * 4 + 1][lm] = v.y;
            As[lk + j * 4 + 2][lm] = v.z;
            As[lk + j * 4 + 3][lm] = v.w;
        }
#pragma unroll
        for (int j = 0; j < 4; j++) {
            float4 v = *(const float4*)(W1 + (size_t)(k0 + wk) * 64 + wn + j * 4);
            Bs[wk][wn + j * 4 + 0] = v.x;
            Bs[wk][wn + j * 4 + 1] = v.y;
            Bs[wk][wn + j * 4 + 2] = v.z;
            Bs[wk][wn + j * 4 + 3] = v.w;
        }
        __syncthreads();
#pragma unroll
        for (int kk = 0; kk < 64; kk++) {
            float4 a = *(const float4*)&As[kk][ty * 4];
            float4 b = *(const float4*)&Bs[kk][tx * 4];
            acc[0][0] += a.x * b.x; acc[0][1] += a.x * b.y; acc[0][2] += a.x * b.z; acc[0][3] += a.x * b.w;
            acc[1][0] += a.y * b.x; acc[1][1] += a.y * b.y; acc[1][2] += a.y * b.z; acc[1][3] += a.y * b.w;
            acc[2][0] += a.z * b.x; acc[2][1] += a.z * b.y; acc[2][2] += a.z * b.z; acc[2][3] += a.z * b.w;
            acc[3][0] += a.w * b.x; acc[3][1] += a.w * b.y; acc[3][2] += a.w * b.z; acc[3][3] += a.w * b.w;
        }
        __syncthreads();
    }
    float4 bb = *(const float4*)(b1 + tx * 4);
#pragma unroll
    for (int i = 0; i < 4; i++) {
        z1t[tx * 4 + 0][ty * 4 + i] = leaky(acc[i][0] + bb.x);
        z1t[tx * 4 + 1][ty * 4 + i] = leaky(acc[i][1] + bb.y);
        z1t[tx * 4 + 2][ty * 4 + i] = leaky(acc[i][2] + bb.z);
        z1t[tx * 4 + 3][ty * 4 + i] = leaky(acc[i][3] + bb.w);
    }
    __syncthreads();

    if (tid < 64) {
        int n = n0 + tid;
        if (n < NN) {
            float zc[NC_];
#pragma unroll
            for (int c = 0; c < NC_; c++) zc[c] = b2[c];
            for (int k = 0; k < 64; k++) {
                float zv = z1t[k][tid];
#pragma unroll
                for (int c = 0; c < NC_; c++) zc[c] += zv * W2[k * NC_ + c];
            }
            float m = zc[0];
#pragma unroll
            for (int c = 1; c < NC_; c++) m = fmaxf(m, zc[c]);
            float ssum = 0.f;
#pragma unroll
            for (int c = 0; c < NC_; c++) { zc[c] = __expf(zc[c] - m) + EPS_; ssum += zc[c]; }
            float inv = 1.f / ssum;
#pragma unroll
            for (int c = 0; c < NC_; c++) out[1000 + (size_t)n * NC_ + c] = zc[c] * inv;
        }
    }
}

// ---------------- group boundaries (batch is sorted) ----------------
__global__ void gstart_kernel(const int* __restrict__ batch, int* __restrict__ gstart) {
    int n = blockIdx.x * 256 + threadIdx.x;
    if (n >= NN) return;
    int b = batch[n];
    int bp = (n == 0) ? -1 : batch[n - 1];
    for (int g = bp + 1; g <= b; g++) gstart[g] = n;
    if (n == NN - 1) {
        for (int g = b + 1; g <= NG_; g++) gstart[g] = NN;
    }
}

// ---------------- group mean + log: one block per group ----------------
__global__ __launch_bounds__(256) void group_mean(const float* __restrict__ preds,
                                                  const int* __restrict__ gstart,
                                                  float* __restrict__ out) {
    __shared__ float red[16][16];
    int g = blockIdx.x;
    int t = threadIdx.x;
    int c = t & 15, chunk = t >> 4;
    int gs = gstart[g], ge = gstart[g + 1];
    float s = 0.f;
    if (c < NC_) {
        for (int n = gs + chunk; n < ge; n += 16) s += preds[(size_t)n * NC_ + c];
    }
    red[chunk][c] = s;
    __syncthreads();
    if (t < NC_) {
        float tot = 0.f;
#pragma unroll
        for (int j = 0; j < 16; j++) tot += red[j][t];
        out[g * NC_ + t] = __logf(tot / (float)(ge - gs));
    }
}

extern "C" void kernel_launch(void* const* d_in, const int* in_sizes, int n_in,
                              void* d_out, int out_size, void* d_ws, size_t ws_size,
                              hipStream_t stream) {
    const float* x      = (const float*)d_in[0];
    const int*   midx   = (const int*)d_in[1];
    const int*   batch  = (const int*)d_in[2];
    const float* W_feat = (const float*)d_in[3];
    const float* phi    = (const float*)d_in[4];
    const float* W1     = (const float*)d_in[5];
    const float* b1     = (const float*)d_in[6];
    const float* W2     = (const float*)d_in[7];
    const float* b2     = (const float*)d_in[8];
    const int* src = midx;
    const int* dst = midx + EE;
    float* out = (float*)d_out;

    char* p = (char*)d_ws;
    auto alloc = [&](size_t bytes) { void* r = (void*)p; p += (bytes + 255) & ~(size_t)255; return r; };
    ushortT* hbf      = (ushortT*)alloc((size_t)NN * HD_ * 2);
    float*   aggG     = (float*)alloc((size_t)NN * HD_ * 4);
    float4*  edge_w   = (float4*)alloc((size_t)EE * 16);
    int*     edge_dst = (int*)alloc((size_t)EE * 4);
    ushortT* wt       = (ushortT*)alloc((size_t)DIN_ * HD_ * 2);
    float*   a_s      = (float*)alloc((size_t)NN * 4 * 4);
    float*   a_d      = (float*)alloc((size_t)NN * 4 * 4);
    int*     deg      = (int*)alloc((size_t)NN * 4);
    int*     offs     = (int*)alloc((size_t)(NN + 1) * 4);
    int*     cursor   = (int*)alloc((size_t)NN * 4);
    int*     gstart   = (int*)alloc((size_t)(NG_ + 1) * 4);

    init_zero<<<(NN + 255) / 256, 256, 0, stream>>>(deg, cursor);
    prep_w<<<(DIN_ * HD_ + 255) / 256, 256, 0, stream>>>(W_feat, wt);
    gemm_h_mfma<<<dim3((NN + 127) / 128, HD_ / 128), 256, 0, stream>>>(x, wt, hbf);
    attn_scores<<<(NN + 3) / 4, 256, 0, stream>>>(hbf, phi, a_s, a_d);
    hist_deg<<<(EE + 255) / 256, 256, 0, stream>>>(src, deg);
    scan_off<<<1, 1024, 0, stream>>>(deg, offs);
    fill_edges<<<(EE + 255) / 256, 256, 0, stream>>>(src, dst, offs, cursor, a_s, a_d,
                                                     edge_dst, edge_w);
    agg_kernel<<<NN / 4, 256, 0, stream>>>(hbf, offs, edge_dst, edge_w, aggG);
    mlp_kernel<<<(NN + 63) / 64, 256, 0, stream>>>(aggG, W1, b1, W2, b2, out);
    gstart_kernel<<<(NN + 255) / 256, 256, 0, stream>>>(batch, gstart);
    group_mean<<<NG_, 256, 0, stream>>>(out + 1000, gstart, out);
}

// Round 6
// 332.495 us; speedup vs baseline: 2.3812x; 1.1414x over previous
//
#include <hip/hip_runtime.h>
#include <hip/hip_bf16.h>
#include <cstdint>

#define NN   50000
#define EE   800000
#define DIN_ 256
#define HD_  256     // H*DH
#define DH_  64
#define NH_  4
#define NC_  10
#define NG_  100
#define EPS_ 1e-4f
#define SLOPE_ 0.01f
#define AROW 40      // LDS row stride in ushorts (32 data + 8 pad)
#define NBLK 49      // ceil(NN/1024) scan blocks

typedef unsigned short ushortT;
typedef __attribute__((ext_vector_type(8))) short short8;
typedef __attribute__((ext_vector_type(4))) float f32x4;

__device__ __forceinline__ float leaky(float x) { return x >= 0.f ? x : SLOPE_ * x; }
__device__ __forceinline__ float sigm(float x)  { return 1.f / (1.f + __expf(-x)); }
__device__ __forceinline__ float b2f(ushortT u) { return __uint_as_float(((unsigned)u) << 16); }
__device__ __forceinline__ float bflo(unsigned u) { return __uint_as_float(u << 16); }
__device__ __forceinline__ float bfhi(unsigned u) { return __uint_as_float(u & 0xffff0000u); }
__device__ __forceinline__ ushortT f2b(float f) {            // RNE fp32->bf16
    unsigned u = __float_as_uint(f);
    u += 0x7fffu + ((u >> 16) & 1u);
    return (ushortT)(u >> 16);
}

// ---------------- setup: zero deg/cursor + transpose W_feat to bf16 + gstart ----------------
__global__ void setup_kernel(int* deg, int* cursor,
                             const float* __restrict__ W, ushortT* __restrict__ wt,
                             const int* __restrict__ batch, int* __restrict__ gstart) {
    int i = blockIdx.x * 256 + threadIdx.x;   // grid covers 65536
    if (i < NN) {
        deg[i] = 0; cursor[i] = 0;
        int b = batch[i];
        int bp = (i == 0) ? -1 : batch[i - 1];
        for (int g = bp + 1; g <= b; g++) gstart[g] = i;
        if (i == NN - 1) {
            for (int g = b + 1; g <= NG_; g++) gstart[g] = NN;
        }
    }
    if (i < DIN_ * HD_) {
        int k = i >> 8, n = i & 255;
        wt[n * DIN_ + k] = f2b(W[i]);
    }
}

// ---------------- MFMA GEMM: hbf = bf16( x @ W_feat ) ----------------
__global__ __launch_bounds__(256) void gemm_h_mfma(const float* __restrict__ x,
                                                   const ushortT* __restrict__ wt,
                                                   ushortT* __restrict__ hbf) {
    __shared__ ushortT A_lds[128 * AROW];
    __shared__ ushortT B_lds[128 * AROW];
    const int tid  = threadIdx.x;
    const int wave = tid >> 6, lane = tid & 63;
    const int wm = wave >> 1, wn = wave & 1;
    const int row0 = blockIdx.x * 128;
    const int col0 = blockIdx.y * 128;
    const int q = lane >> 4, l16 = lane & 15;

    f32x4 acc[4][4];
#pragma unroll
    for (int i = 0; i < 4; i++)
#pragma unroll
        for (int j = 0; j < 4; j++) acc[i][j] = (f32x4){0.f, 0.f, 0.f, 0.f};

    const int lm  = tid >> 1;
    const int lko = (tid & 1) * 16;

    for (int k0 = 0; k0 < DIN_; k0 += 32) {
        __syncthreads();
        {
            int gr = row0 + lm;
            float4 a0 = make_float4(0.f,0.f,0.f,0.f), a1 = a0, a2 = a0, a3 = a0;
            if (gr < NN) {
                const float4* xp = (const float4*)(x + (size_t)gr * DIN_ + k0 + lko);
                a0 = xp[0]; a1 = xp[1]; a2 = xp[2]; a3 = xp[3];
            }
            ushortT* ap = &A_lds[lm * AROW + lko];
            *(ushort4*)(ap + 0)  = make_ushort4(f2b(a0.x), f2b(a0.y), f2b(a0.z), f2b(a0.w));
            *(ushort4*)(ap + 4)  = make_ushort4(f2b(a1.x), f2b(a1.y), f2b(a1.z), f2b(a1.w));
            *(ushort4*)(ap + 8)  = make_ushort4(f2b(a2.x), f2b(a2.y), f2b(a2.z), f2b(a2.w));
            *(ushort4*)(ap + 12) = make_ushort4(f2b(a3.x), f2b(a3.y), f2b(a3.z), f2b(a3.w));
        }
        {
            const uint4* wp = (const uint4*)(wt + (size_t)(col0 + lm) * DIN_ + k0 + lko);
            uint4 b0 = wp[0], b1 = wp[1];
            *(uint4*)&B_lds[lm * AROW + lko + 0] = b0;
            *(uint4*)&B_lds[lm * AROW + lko + 8] = b1;
        }
        __syncthreads();

        short8 af[4], bf[4];
#pragma unroll
        for (int mi = 0; mi < 4; mi++)
            af[mi] = *(const short8*)&A_lds[(wm * 64 + mi * 16 + l16) * AROW + q * 8];
#pragma unroll
        for (int ni = 0; ni < 4; ni++)
            bf[ni] = *(const short8*)&B_lds[(wn * 64 + ni * 16 + l16) * AROW + q * 8];
#pragma unroll
        for (int mi = 0; mi < 4; mi++)
#pragma unroll
            for (int ni = 0; ni < 4; ni++)
                acc[mi][ni] = __builtin_amdgcn_mfma_f32_16x16x32_bf16(af[mi], bf[ni], acc[mi][ni], 0, 0, 0);
    }

#pragma unroll
    for (int mi = 0; mi < 4; mi++) {
        int rbase = row0 + wm * 64 + mi * 16 + q * 4;
#pragma unroll
        for (int ni = 0; ni < 4; ni++) {
            int c = col0 + wn * 64 + ni * 16 + l16;
#pragma unroll
            for (int r = 0; r < 4; r++) {
                int gr = rbase + r;
                if (gr < NN) hbf[(size_t)gr * HD_ + c] = f2b(acc[mi][ni][r]);
            }
        }
    }
}

// ---------------- attention scores a_s, a_d (bf16 h) ----------------
__global__ __launch_bounds__(256) void attn_scores(const ushortT* __restrict__ hbf,
                                                   const float* __restrict__ phi,
                                                   float* __restrict__ a_s,
                                                   float* __restrict__ a_d) {
    int wv = threadIdx.x >> 6, lane = threadIdx.x & 63;
    int n = blockIdx.x * 4 + wv;
    if (n >= NN) return;
    int h = lane >> 4;
    int d0 = (lane & 15) * 4;
    ushort4 hv = *(const ushort4*)(hbf + (size_t)n * HD_ + h * DH_ + d0);
    float hw[4] = { b2f(hv.x), b2f(hv.y), b2f(hv.z), b2f(hv.w) };
    float ss = 0.f, sd = 0.f;
#pragma unroll
    for (int i = 0; i < 4; i++) {
        ss += hw[i] * phi[h * 128 + d0 + i];
        sd += hw[i] * phi[h * 128 + 64 + d0 + i];
    }
#pragma unroll
    for (int o = 1; o < 16; o <<= 1) {
        ss += __shfl_xor(ss, o);
        sd += __shfl_xor(sd, o);
    }
    if ((lane & 15) == 0) {
        a_s[n * 4 + h] = ss;
        a_d[n * 4 + h] = sd;
    }
}

// ---------------- CSR build: hist + 3-phase scan + fill ----------------
__global__ void hist_deg(const int* __restrict__ src, int* __restrict__ deg) {
    int e = blockIdx.x * 256 + threadIdx.x;
    if (e < EE) atomicAdd(&deg[src[e]], 1);
}

// phase 1: per-block scan (49 blocks x 1024), exclusive-within-block + block sums
__global__ __launch_bounds__(1024) void scan_blk(const int* __restrict__ deg,
                                                 int* __restrict__ offsP,
                                                 int* __restrict__ bsum) {
    __shared__ int wsum[16];
    int t = threadIdx.x, lane = t & 63, w = t >> 6;
    int i = blockIdx.x * 1024 + t;
    int v = (i < NN) ? deg[i] : 0;
    int incl = v;
#pragma unroll
    for (int o = 1; o < 64; o <<= 1) {
        int u = __shfl_up(incl, o);
        if (lane >= o) incl += u;
    }
    if (lane == 63) wsum[w] = incl;
    __syncthreads();
    int woff = 0, total = 0;
#pragma unroll
    for (int j = 0; j < 16; j++) {
        int s = wsum[j];
        if (j < w) woff += s;
        total += s;
    }
    if (i < NN) offsP[i] = woff + incl - v;
    if (t == 0) bsum[blockIdx.x] = total;
}

// phase 2: scan the 49 block sums (1 block, 64 threads)
__global__ void scan_top(const int* __restrict__ bsum, int* __restrict__ boff) {
    int t = threadIdx.x;
    int v = (t < NBLK) ? bsum[t] : 0;
    int incl = v;
#pragma unroll
    for (int o = 1; o < 64; o <<= 1) {
        int u = __shfl_up(incl, o);
        if (t >= o) incl += u;
    }
    if (t < NBLK) boff[t] = incl - v;
}

// phase 3: final offsets
__global__ void scan_fix(const int* __restrict__ offsP, const int* __restrict__ boff,
                         int* __restrict__ offs) {
    int i = blockIdx.x * 256 + threadIdx.x;
    if (i < NN) offs[i] = offsP[i] + boff[i >> 10];
    if (i == NN) offs[NN] = EE;
}

__global__ void fill_edges(const int* __restrict__ src, const int* __restrict__ dstA,
                           const int* __restrict__ offs, int* __restrict__ cursor,
                           const float* __restrict__ a_s, const float* __restrict__ a_d,
                           int* __restrict__ edge_dst, float4* __restrict__ edge_w) {
    int e = blockIdx.x * 256 + threadIdx.x;
    if (e >= EE) return;
    int s = src[e], d = dstA[e];
    int p = offs[s] + atomicAdd(&cursor[s], 1);
    edge_dst[p] = d;
    float4 as4 = *(const float4*)(a_s + (size_t)s * 4);
    float4 ad4 = *(const float4*)(a_d + (size_t)d * 4);
    float4 w;
    w.x = sigm(leaky(as4.x + ad4.x));
    w.y = sigm(leaky(as4.y + ad4.y));
    w.z = sigm(leaky(as4.z + ad4.z));
    w.w = sigm(leaky(as4.w + ad4.w));
    edge_w[p] = w;
}

// ---------------- aggregation: one wave per node, bf16 gather, bf16 out ----------------
__global__ __launch_bounds__(256) void agg_kernel(const ushortT* __restrict__ hbf,
                                                  const int* __restrict__ offs,
                                                  const int* __restrict__ edge_dst,
                                                  const float4* __restrict__ edge_w,
                                                  ushortT* __restrict__ aggB) {
    int wv = threadIdx.x >> 6, lane = threadIdx.x & 63;
    int n = blockIdx.x * 4 + wv;   // grid 12500*4 == 50000
    int e0 = offs[n], e1 = offs[n + 1];
    int hsel = lane >> 4;
    float4 acc = make_float4(0.f, 0.f, 0.f, 0.f);
    const ushortT* hbase = hbf + (size_t)lane * 4;

    int i = e0;
    for (; i + 4 <= e1; i += 4) {
        int d0 = edge_dst[i], d1 = edge_dst[i + 1], d2 = edge_dst[i + 2], d3 = edge_dst[i + 3];
        float4 w0 = edge_w[i], w1 = edge_w[i + 1], w2 = edge_w[i + 2], w3 = edge_w[i + 3];
        ushort4 h0 = *(const ushort4*)(hbase + (size_t)d0 * HD_);
        ushort4 h1 = *(const ushort4*)(hbase + (size_t)d1 * HD_);
        ushort4 h2 = *(const ushort4*)(hbase + (size_t)d2 * HD_);
        ushort4 h3 = *(const ushort4*)(hbase + (size_t)d3 * HD_);
        float s0 = hsel == 0 ? w0.x : hsel == 1 ? w0.y : hsel == 2 ? w0.z : w0.w;
        float s1 = hsel == 0 ? w1.x : hsel == 1 ? w1.y : hsel == 2 ? w1.z : w1.w;
        float s2 = hsel == 0 ? w2.x : hsel == 1 ? w2.y : hsel == 2 ? w2.z : w2.w;
        float s3 = hsel == 0 ? w3.x : hsel == 1 ? w3.y : hsel == 2 ? w3.z : w3.w;
        acc.x += b2f(h0.x) * s0; acc.y += b2f(h0.y) * s0; acc.z += b2f(h0.z) * s0; acc.w += b2f(h0.w) * s0;
        acc.x += b2f(h1.x) * s1; acc.y += b2f(h1.y) * s1; acc.z += b2f(h1.z) * s1; acc.w += b2f(h1.w) * s1;
        acc.x += b2f(h2.x) * s2; acc.y += b2f(h2.y) * s2; acc.z += b2f(h2.z) * s2; acc.w += b2f(h2.w) * s2;
        acc.x += b2f(h3.x) * s3; acc.y += b2f(h3.y) * s3; acc.z += b2f(h3.z) * s3; acc.w += b2f(h3.w) * s3;
    }
    for (; i < e1; i++) {
        int d = edge_dst[i];
        float4 w4 = edge_w[i];
        ushort4 hv = *(const ushort4*)(hbase + (size_t)d * HD_);
        float s = hsel == 0 ? w4.x : hsel == 1 ? w4.y : hsel == 2 ? w4.z : w4.w;
        acc.x += b2f(hv.x) * s; acc.y += b2f(hv.y) * s; acc.z += b2f(hv.z) * s; acc.w += b2f(hv.w) * s;
    }
    ushort4 o4 = make_ushort4(f2b(acc.x), f2b(acc.y), f2b(acc.z), f2b(acc.w));
    *(ushort4*)(aggB + (size_t)n * HD_ + lane * 4) = o4;
}

// ---------------- MLP + softmax: bf16 agg in, preds out (NO atomics) ----------------
__global__ __launch_bounds__(256) void mlp_kernel(const ushortT* __restrict__ aggB,
                                                  const float* __restrict__ W1,
                                                  const float* __restrict__ b1,
                                                  const float* __restrict__ W2,
                                                  const float* __restrict__ b2,
                                                  float* __restrict__ out) {
    __shared__ float As[64][68];
    __shared__ float Bs[64][68];
    __shared__ float z1t[64][68];
    const int tid = threadIdx.x;
    const int n0 = blockIdx.x * 64;
    const int tx = tid & 15, ty = tid >> 4;
    const int lm = tid >> 2, lk = (tid & 3) * 16;
    const int wk = tid >> 2, wn = (tid & 3) * 16;

    float acc[4][4] = {};

    for (int k0 = 0; k0 < 256; k0 += 64) {
        int grow = n0 + lm;
        {
            uint4 r0 = make_uint4(0u,0u,0u,0u), r1 = r0;
            if (grow < NN) {
                const uint4* ap = (const uint4*)(aggB + (size_t)grow * HD_ + k0 + lk);
                r0 = ap[0]; r1 = ap[1];
            }
            As[lk + 0][lm] = bflo(r0.x); As[lk + 1][lm] = bfhi(r0.x);
            As[lk + 2][lm] = bflo(r0.y); As[lk + 3][lm] = bfhi(r0.y);
            As[lk + 4][lm] = bflo(r0.z); As[lk + 5][lm] = bfhi(r0.z);
            As[lk + 6][lm] = bflo(r0.w); As[lk + 7][lm] = bfhi(r0.w);
            As[lk + 8][lm] = bflo(r1.x); As[lk + 9][lm] = bfhi(r1.x);
            As[lk + 10][lm] = bflo(r1.y); As[lk + 11][lm] = bfhi(r1.y);
            As[lk + 12][lm] = bflo(r1.z); As[lk + 13][lm] = bfhi(r1.z);
            As[lk + 14][lm] = bflo(r1.w); As[lk + 15][lm] = bfhi(r1.w);
        }
#pragma unroll
        for (int j = 0; j < 4; j++) {
            float4 v = *(const float4*)(W1 + (size_t)(k0 + wk) * 64 + wn + j * 4);
            Bs[wk][wn + j * 4 + 0] = v.x;
            Bs[wk][wn + j * 4 + 1] = v.y;
            Bs[wk][wn + j * 4 + 2] = v.z;
            Bs[wk][wn + j * 4 + 3] = v.w;
        }
        __syncthreads();
#pragma unroll
        for (int kk = 0; kk < 64; kk++) {
            float4 a = *(const float4*)&As[kk][ty * 4];
            float4 b = *(const float4*)&Bs[kk][tx * 4];
            acc[0][0] += a.x * b.x; acc[0][1] += a.x * b.y; acc[0][2] += a.x * b.z; acc[0][3] += a.x * b.w;
            acc[1][0] += a.y * b.x; acc[1][1] += a.y * b.y; acc[1][2] += a.y * b.z; acc[1][3] += a.y * b.w;
            acc[2][0] += a.z * b.x; acc[2][1] += a.z * b.y; acc[2][2] += a.z * b.z; acc[2][3] += a.z * b.w;
            acc[3][0] += a.w * b.x; acc[3][1] += a.w * b.y; acc[3][2] += a.w * b.z; acc[3][3] += a.w * b.w;
        }
        __syncthreads();
    }
    float4 bb = *(const float4*)(b1 + tx * 4);
#pragma unroll
    for (int i = 0; i < 4; i++) {
        z1t[tx * 4 + 0][ty * 4 + i] = leaky(acc[i][0] + bb.x);
        z1t[tx * 4 + 1][ty * 4 + i] = leaky(acc[i][1] + bb.y);
        z1t[tx * 4 + 2][ty * 4 + i] = leaky(acc[i][2] + bb.z);
        z1t[tx * 4 + 3][ty * 4 + i] = leaky(acc[i][3] + bb.w);
    }
    __syncthreads();

    if (tid < 64) {
        int n = n0 + tid;
        if (n < NN) {
            float zc[NC_];
#pragma unroll
            for (int c = 0; c < NC_; c++) zc[c] = b2[c];
            for (int k = 0; k < 64; k++) {
                float zv = z1t[k][tid];
#pragma unroll
                for (int c = 0; c < NC_; c++) zc[c] += zv * W2[k * NC_ + c];
            }
            float m = zc[0];
#pragma unroll
            for (int c = 1; c < NC_; c++) m = fmaxf(m, zc[c]);
            float ssum = 0.f;
#pragma unroll
            for (int c = 0; c < NC_; c++) { zc[c] = __expf(zc[c] - m) + EPS_; ssum += zc[c]; }
            float inv = 1.f / ssum;
#pragma unroll
            for (int c = 0; c < NC_; c++) out[1000 + (size_t)n * NC_ + c] = zc[c] * inv;
        }
    }
}

// ---------------- group mean + log: one block per group ----------------
__global__ __launch_bounds__(256) void group_mean(const float* __restrict__ preds,
                                                  const int* __restrict__ gstart,
                                                  float* __restrict__ out) {
    __shared__ float red[16][16];
    int g = blockIdx.x;
    int t = threadIdx.x;
    int c = t & 15, chunk = t >> 4;
    int gs = gstart[g], ge = gstart[g + 1];
    float s = 0.f;
    if (c < NC_) {
        for (int n = gs + chunk; n < ge; n += 16) s += preds[(size_t)n * NC_ + c];
    }
    red[chunk][c] = s;
    __syncthreads();
    if (t < NC_) {
        float tot = 0.f;
#pragma unroll
        for (int j = 0; j < 16; j++) tot += red[j][t];
        out[g * NC_ + t] = __logf(tot / (float)(ge - gs));
    }
}

extern "C" void kernel_launch(void* const* d_in, const int* in_sizes, int n_in,
                              void* d_out, int out_size, void* d_ws, size_t ws_size,
                              hipStream_t stream) {
    const float* x      = (const float*)d_in[0];
    const int*   midx   = (const int*)d_in[1];
    const int*   batch  = (const int*)d_in[2];
    const float* W_feat = (const float*)d_in[3];
    const float* phi    = (const float*)d_in[4];
    const float* W1     = (const float*)d_in[5];
    const float* b1     = (const float*)d_in[6];
    const float* W2     = (const float*)d_in[7];
    const float* b2     = (const float*)d_in[8];
    const int* src = midx;
    const int* dst = midx + EE;
    float* out = (float*)d_out;

    char* p = (char*)d_ws;
    auto alloc = [&](size_t bytes) { void* r = (void*)p; p += (bytes + 255) & ~(size_t)255; return r; };
    ushortT* hbf      = (ushortT*)alloc((size_t)NN * HD_ * 2);
    ushortT* aggB     = (ushortT*)alloc((size_t)NN * HD_ * 2);
    float4*  edge_w   = (float4*)alloc((size_t)EE * 16);
    int*     edge_dst = (int*)alloc((size_t)EE * 4);
    ushortT* wt       = (ushortT*)alloc((size_t)DIN_ * HD_ * 2);
    float*   a_s      = (float*)alloc((size_t)NN * 4 * 4);
    float*   a_d      = (float*)alloc((size_t)NN * 4 * 4);
    int*     deg      = (int*)alloc((size_t)NN * 4);
    int*     offsP    = (int*)alloc((size_t)NN * 4);
    int*     offs     = (int*)alloc((size_t)(NN + 1) * 4);
    int*     cursor   = (int*)alloc((size_t)NN * 4);
    int*     bsum     = (int*)alloc((size_t)NBLK * 4);
    int*     boff     = (int*)alloc((size_t)64 * 4);
    int*     gstart   = (int*)alloc((size_t)(NG_ + 1) * 4);

    setup_kernel<<<256, 256, 0, stream>>>(deg, cursor, W_feat, wt, batch, gstart);
    gemm_h_mfma<<<dim3((NN + 127) / 128, HD_ / 128), 256, 0, stream>>>(x, wt, hbf);
    attn_scores<<<(NN + 3) / 4, 256, 0, stream>>>(hbf, phi, a_s, a_d);
    hist_deg<<<(EE + 255) / 256, 256, 0, stream>>>(src, deg);
    scan_blk<<<NBLK, 1024, 0, stream>>>(deg, offsP, bsum);
    scan_top<<<1, 64, 0, stream>>>(bsum, boff);
    scan_fix<<<(NN + 256) / 256, 256, 0, stream>>>(offsP, boff, offs);
    fill_edges<<<(EE + 255) / 256, 256, 0, stream>>>(src, dst, offs, cursor, a_s, a_d,
                                                     edge_dst, edge_w);
    agg_kernel<<<NN / 4, 256, 0, stream>>>(hbf, offs, edge_dst, edge_w, aggB);
    mlp_kernel<<<(NN + 63) / 64, 256, 0, stream>>>(aggB, W1, b1, W2, b2, out);
    group_mean<<<NG_, 256, 0, stream>>>(out + 1000, gstart, out);
}